// Round 7
// baseline (278.334 us; speedup 1.0000x reference)
//
#include <hip/hip_runtime.h>
#include <hip/hip_bf16.h>

#define DMODEL 256
#define DCH 128
#define NLAYER 3
#define LN_EPS 1e-5f

typedef float f32x4 __attribute__((ext_vector_type(4)));
typedef short s16x8 __attribute__((ext_vector_type(8)));

__device__ __forceinline__ unsigned short f2bf(float f) {
  unsigned int u = __float_as_uint(f);
  unsigned int r = (u + 0x7FFF + ((u >> 16) & 1)) >> 16;  // RNE
  return (unsigned short)r;
}

__device__ __forceinline__ unsigned int pk2bf(float x, float y) {
  return ((unsigned int)f2bf(y) << 16) | f2bf(x);
}

// ---------------- CSR build ----------------

__global__ __launch_bounds__(256) void hist_kernel(const int* __restrict__ row,
    const int* __restrict__ col, int* cnt_row, int* cnt_col, int E) {
  int e = blockIdx.x * 256 + threadIdx.x;
  if (e < E) {
    atomicAdd(&cnt_row[row[e]], 1);
    atomicAdd(&cnt_col[col[e]], 1);
  }
}

// one block: dis = rsqrt(cnt_row+1); exclusive scan of cnt_col -> indptr, cursor
__global__ __launch_bounds__(256) void scan_dis_kernel(
    const int* __restrict__ cnt_col, const int* __restrict__ cnt_row,
    int* __restrict__ indptr, int* __restrict__ cursor,
    float* __restrict__ dis, int N, int E) {
  int t = threadIdx.x;
  for (int i = t; i < N; i += 256) dis[i] = rsqrtf((float)(cnt_row[i] + 1));

  const int PER = (N + 255) / 256;
  int start = t * PER;
  int sum = 0;
  for (int k = 0; k < PER; ++k) {
    int i = start + k;
    if (i < N) sum += cnt_col[i];
  }
  int lane = t & 63, wid = t >> 6;
  int inc = sum;
#pragma unroll
  for (int off = 1; off < 64; off <<= 1) {
    int v = __shfl_up(inc, off);
    if (lane >= off) inc += v;
  }
  __shared__ int wsum[4];
  if (lane == 63) wsum[wid] = inc;
  __syncthreads();
  int woff = 0;
  for (int w = 0; w < wid; ++w) woff += wsum[w];
  int run = woff + inc - sum;
  for (int k = 0; k < PER; ++k) {
    int i = start + k;
    if (i < N) {
      indptr[i] = run;
      cursor[i] = run;
      run += cnt_col[i];
    }
  }
  if (t == 255) indptr[N] = E;
}

__global__ __launch_bounds__(256) void fill_kernel(const int* __restrict__ row,
    const int* __restrict__ col, int* cursor, int* __restrict__ idx, int E) {
  int e = blockIdx.x * 256 + threadIdx.x;
  if (e < E) {
    int pos = atomicAdd(&cursor[col[e]], 1);
    idx[pos] = row[e];
  }
}

// ---------------- per-layer linear -> bf16 ht, via MFMA, no LDS ----------------
// grid: (ceil(N/32), 2); 256 threads = 4 waves.
// wave w: mtile = w&1 (rows 16*mtile..+15), colgroup = w>>1 (cols 64*cg..+63).
// Each wave: 4 accumulators (16x16 tiles) over K=128 in 4 steps of 32.
// A frag: lane holds x[arow][k=(l>>4)*8..+7]; B frag: W[bcol][k=(l>>4)*8..+7].

__global__ __launch_bounds__(256) void gemm_mfma_kernel(const float* __restrict__ x,
    const float* __restrict__ Wc, const float* __restrict__ bc,
    const float* __restrict__ Wp, const float* __restrict__ bp,
    unsigned short* __restrict__ ht, int layer, int Nn) {
  int h = blockIdx.y;
  const float* __restrict__ W = (h ? Wp : Wc) + (size_t)layer * DCH * DCH;
  const float* __restrict__ b = (h ? bp : bc) + (size_t)layer * DCH;
  int i0 = blockIdx.x * 32;
  int t = threadIdx.x;
  int w = t >> 6;
  int lane = t & 63;
  int mt = w & 1;
  int cg = w >> 1;
  int lrow = lane & 15;
  int kgrp = lane >> 4;  // 0..3, k-chunk of 8

  int arow = i0 + mt * 16 + lrow;
  int arow_c = min(arow, Nn - 1);
  const float* ap = x + (size_t)arow_c * DMODEL + h * DCH + kgrp * 8;

  int bcol[4];
  const float* bp_[4];
  f32x4 acc[4];
#pragma unroll
  for (int nt = 0; nt < 4; ++nt) {
    bcol[nt] = cg * 64 + nt * 16 + lrow;
    bp_[nt] = W + bcol[nt] * DCH + kgrp * 8;
    float bias = b[bcol[nt]];
    acc[nt] = (f32x4){bias, bias, bias, bias};
  }

  union U8 { s16x8 v; unsigned int u[4]; };

#pragma unroll
  for (int kt = 0; kt < 4; ++kt) {
    float4 a0 = *(const float4*)(ap + kt * 32);
    float4 a1 = *(const float4*)(ap + kt * 32 + 4);
    U8 af;
    af.u[0] = pk2bf(a0.x, a0.y);
    af.u[1] = pk2bf(a0.z, a0.w);
    af.u[2] = pk2bf(a1.x, a1.y);
    af.u[3] = pk2bf(a1.z, a1.w);
#pragma unroll
    for (int nt = 0; nt < 4; ++nt) {
      float4 b0 = *(const float4*)(bp_[nt] + kt * 32);
      float4 b1 = *(const float4*)(bp_[nt] + kt * 32 + 4);
      U8 bf;
      bf.u[0] = pk2bf(b0.x, b0.y);
      bf.u[1] = pk2bf(b0.z, b0.w);
      bf.u[2] = pk2bf(b1.x, b1.y);
      bf.u[3] = pk2bf(b1.z, b1.w);
      acc[nt] = __builtin_amdgcn_mfma_f32_16x16x32_bf16(af.v, bf.v, acc[nt], 0, 0, 0);
    }
  }

  // D: row = mt*16 + (lane>>4)*4 + j, col = bcol[nt]
#pragma unroll
  for (int nt = 0; nt < 4; ++nt) {
#pragma unroll
    for (int j = 0; j < 4; ++j) {
      int gi = i0 + mt * 16 + kgrp * 4 + j;
      if (gi < Nn) ht[(size_t)gi * DMODEL + h * DCH + bcol[nt]] = f2bf(acc[nt][j]);
    }
  }
}

// ---------------- aggregation + LayerNorm (+ReLU) + residual ----------------
// 128 threads per node; thread t owns dims 2t, 2t+1.

__device__ __forceinline__ void bf2x(unsigned int u, float w, float& a0, float& a1) {
  a0 += w * __uint_as_float(u << 16);
  a1 += w * __uint_as_float(u & 0xFFFF0000u);
}

__global__ __launch_bounds__(128) void agg_kernel(const float* __restrict__ xin,
    const unsigned short* __restrict__ ht, float* __restrict__ xout,
    const float* __restrict__ dis, const int* __restrict__ indptr,
    const int* __restrict__ idx, const float* __restrict__ gamma,
    const float* __restrict__ beta, const int* __restrict__ noi,
    int use_noi, int relu) {
  int b = blockIdx.x;
  int i = use_noi ? noi[b] : b;
  int t = threadIdx.x;
  float di = dis[i];
  size_t rbase = (size_t)i * DMODEL + 2 * t;

  unsigned int us = *(const unsigned int*)&ht[rbase];
  float w2s = di * di;
  float acc0 = w2s * __uint_as_float(us << 16);
  float acc1 = w2s * __uint_as_float(us & 0xFFFF0000u);

  int s = indptr[i], e = indptr[i + 1];
  __shared__ int s_src[128];
  __shared__ float s_w[128];
  for (int base = s; base < e; base += 128) {
    int n = min(128, e - base);
    __syncthreads();
    if (t < n) {
      int sr = idx[base + t];
      s_src[t] = sr;
      s_w[t] = dis[sr] * di;
    }
    __syncthreads();
    int j = 0;
    for (; j + 4 <= n; j += 4) {
      int  q0 = s_src[j], q1 = s_src[j + 1], q2 = s_src[j + 2], q3 = s_src[j + 3];
      float w0 = s_w[j], w1 = s_w[j + 1], w2 = s_w[j + 2], w3 = s_w[j + 3];
      unsigned int u0 = *(const unsigned int*)&ht[(size_t)q0 * DMODEL + 2 * t];
      unsigned int u1 = *(const unsigned int*)&ht[(size_t)q1 * DMODEL + 2 * t];
      unsigned int u2 = *(const unsigned int*)&ht[(size_t)q2 * DMODEL + 2 * t];
      unsigned int u3 = *(const unsigned int*)&ht[(size_t)q3 * DMODEL + 2 * t];
      bf2x(u0, w0, acc0, acc1);
      bf2x(u1, w1, acc0, acc1);
      bf2x(u2, w2, acc0, acc1);
      bf2x(u3, w3, acc0, acc1);
    }
    for (; j < n; ++j) {
      unsigned int u = *(const unsigned int*)&ht[(size_t)s_src[j] * DMODEL + 2 * t];
      bf2x(u, s_w[j], acc0, acc1);
    }
  }

  // LayerNorm over 256 dims (2 per thread, 128 threads)
  float v1 = acc0 + acc1, v2 = acc0 * acc0 + acc1 * acc1;
#pragma unroll
  for (int o = 32; o > 0; o >>= 1) {
    v1 += __shfl_down(v1, o);
    v2 += __shfl_down(v2, o);
  }
  __shared__ float w1s[2], w2ss[2];
  int wid = t >> 6, lane = t & 63;
  if (lane == 0) { w1s[wid] = v1; w2ss[wid] = v2; }
  __syncthreads();
  float s1 = w1s[0] + w1s[1];
  float s2 = w2ss[0] + w2ss[1];
  float mu = s1 * (1.0f / DMODEL);
  float var = s2 * (1.0f / DMODEL) - mu * mu;
  float rs = rsqrtf(var + LN_EPS);
  float2 g = *(const float2*)&gamma[2 * t];
  float2 bb = *(const float2*)&beta[2 * t];
  float y0 = (acc0 - mu) * rs * g.x + bb.x;
  float y1 = (acc1 - mu) * rs * g.y + bb.y;
  if (relu) { y0 = fmaxf(y0, 0.f); y1 = fmaxf(y1, 0.f); }
  float2 xi = *(const float2*)&xin[rbase];
  size_t ob = (size_t)(use_noi ? b : i) * DMODEL + 2 * t;
  *(float2*)&xout[ob] = make_float2(xi.x + y0, xi.y + y1);
}

extern "C" void kernel_launch(void* const* d_in, const int* in_sizes, int n_in,
                              void* d_out, int out_size, void* d_ws, size_t ws_size,
                              hipStream_t stream) {
  const float* x     = (const float*)d_in[0];
  const int*   edges = (const int*)d_in[1];
  const int*   noi   = (const int*)d_in[2];
  const float* Wc    = (const float*)d_in[3];
  const float* bc    = (const float*)d_in[4];
  const float* Wp    = (const float*)d_in[5];
  const float* bp    = (const float*)d_in[6];
  const float* gamma = (const float*)d_in[7];
  const float* beta  = (const float*)d_in[8];

  int N = in_sizes[0] / DMODEL;
  int E = in_sizes[1] / 2;
  int K = in_sizes[2];
  const int* row = edges;      // source
  const int* col = edges + E;  // destination

  char* base = (char*)d_ws;
  size_t off = 0;
  auto alloc = [&](size_t bytes) -> void* {
    void* p = base + off;
    off += (bytes + 255) & ~(size_t)255;
    return p;
  };

  float*          xA     = (float*)alloc((size_t)N * DMODEL * 4);
  float*          xB     = (float*)alloc((size_t)N * DMODEL * 4);
  unsigned short* htb    = (unsigned short*)alloc((size_t)N * DMODEL * 2);
  float*          dis    = (float*)alloc((size_t)N * 4);
  int*            cnt    = (int*)alloc((size_t)2 * N * 4);  // [row | col]
  int*            indptr = (int*)alloc((size_t)(N + 1) * 4);
  int*            cursor = (int*)alloc((size_t)N * 4);
  int*            idx    = (int*)alloc((size_t)E * 4);

  hipMemsetAsync(cnt, 0, (size_t)2 * N * 4, stream);

  int eb = (E + 255) / 256;
  hist_kernel<<<eb, 256, 0, stream>>>(row, col, cnt, cnt + N, E);
  scan_dis_kernel<<<1, 256, 0, stream>>>(cnt + N, cnt, indptr, cursor, dis, N, E);
  fill_kernel<<<eb, 256, 0, stream>>>(row, col, cursor, idx, E);

  const float* cur_in = x;
  float* bufs[2] = {xA, xB};
  for (int l = 0; l < NLAYER; ++l) {
    dim3 ggrid((N + 31) / 32, 2);
    gemm_mfma_kernel<<<ggrid, 256, 0, stream>>>(cur_in, Wc, bc, Wp, bp, htb, l, N);
    if (l < NLAYER - 1) {
      agg_kernel<<<N, 128, 0, stream>>>(cur_in, htb, bufs[l & 1], dis, indptr, idx,
                                        gamma + (size_t)l * DMODEL,
                                        beta + (size_t)l * DMODEL,
                                        nullptr, 0, 1);
      cur_in = bufs[l & 1];
    } else {
      agg_kernel<<<K, 128, 0, stream>>>(cur_in, htb, (float*)d_out, dis, indptr, idx,
                                        gamma + (size_t)l * DMODEL,
                                        beta + (size_t)l * DMODEL,
                                        noi, 1, 0);
    }
  }
}

// Round 8
// 265.503 us; speedup vs baseline: 1.0483x; 1.0483x over previous
//
#include <hip/hip_runtime.h>

#define DMODEL 256
#define DCH 128
#define NLAYER 3
#define LN_EPS 1e-5f

typedef float f32x4 __attribute__((ext_vector_type(4)));
typedef short s16x8 __attribute__((ext_vector_type(8)));

__device__ __forceinline__ unsigned short f2bf(float f) {
  unsigned int u = __float_as_uint(f);
  unsigned int r = (u + 0x7FFF + ((u >> 16) & 1)) >> 16;  // RNE
  return (unsigned short)r;
}
__device__ __forceinline__ unsigned int pk2bf(float x, float y) {
  return ((unsigned int)f2bf(y) << 16) | f2bf(x);
}
__device__ __forceinline__ float bflo(unsigned int u) { return __uint_as_float(u << 16); }
__device__ __forceinline__ float bfhi(unsigned int u) { return __uint_as_float(u & 0xFFFF0000u); }

// ---------------- CSR hist + bf16 conversions (x, Wc, Wp) ----------------
__global__ __launch_bounds__(256) void hist_cvt_kernel(
    const int* __restrict__ row, const int* __restrict__ col,
    int* cnt_row, int* cnt_col, int E,
    const float* __restrict__ x, unsigned short* __restrict__ xbf, int nx8,
    const float* __restrict__ Wc, unsigned short* __restrict__ Wcb,
    const float* __restrict__ Wp, unsigned short* __restrict__ Wpb, int nw8) {
  int tid = blockIdx.x * 256 + threadIdx.x;
  if (tid < E) {
    atomicAdd(&cnt_row[row[tid]], 1);
    atomicAdd(&cnt_col[col[tid]], 1);
  }
  if (tid < nx8) {
    float4 a = *(const float4*)&x[tid * 8];
    float4 b = *(const float4*)&x[tid * 8 + 4];
    uint4 o = {pk2bf(a.x, a.y), pk2bf(a.z, a.w), pk2bf(b.x, b.y), pk2bf(b.z, b.w)};
    *(uint4*)&xbf[tid * 8] = o;
  }
  if (tid < nw8) {
    float4 a = *(const float4*)&Wc[tid * 8];
    float4 b = *(const float4*)&Wc[tid * 8 + 4];
    uint4 o = {pk2bf(a.x, a.y), pk2bf(a.z, a.w), pk2bf(b.x, b.y), pk2bf(b.z, b.w)};
    *(uint4*)&Wcb[tid * 8] = o;
    a = *(const float4*)&Wp[tid * 8];
    b = *(const float4*)&Wp[tid * 8 + 4];
    uint4 o2 = {pk2bf(a.x, a.y), pk2bf(a.z, a.w), pk2bf(b.x, b.y), pk2bf(b.z, b.w)};
    *(uint4*)&Wpb[tid * 8] = o2;
  }
}

// ---------------- scan + dis (one block) ----------------
__global__ __launch_bounds__(256) void scan_dis_kernel(
    const int* __restrict__ cnt_col, const int* __restrict__ cnt_row,
    int* __restrict__ indptr, int* __restrict__ cursor,
    float* __restrict__ dis, int N, int E) {
  int t = threadIdx.x;
  for (int i = t; i < N; i += 256) dis[i] = rsqrtf((float)(cnt_row[i] + 1));
  const int PER = (N + 255) / 256;
  int start = t * PER;
  int sum = 0;
  for (int k = 0; k < PER; ++k) {
    int i = start + k;
    if (i < N) sum += cnt_col[i];
  }
  int lane = t & 63, wid = t >> 6;
  int inc = sum;
#pragma unroll
  for (int off = 1; off < 64; off <<= 1) {
    int v = __shfl_up(inc, off);
    if (lane >= off) inc += v;
  }
  __shared__ int wsum[4];
  if (lane == 63) wsum[wid] = inc;
  __syncthreads();
  int woff = 0;
  for (int w = 0; w < wid; ++w) woff += wsum[w];
  int run = woff + inc - sum;
  for (int k = 0; k < PER; ++k) {
    int i = start + k;
    if (i < N) {
      indptr[i] = run;
      cursor[i] = run;
      run += cnt_col[i];
    }
  }
  if (t == 255) indptr[N] = E;
}

__global__ __launch_bounds__(256) void fill_kernel(const int* __restrict__ row,
    const int* __restrict__ col, int* cursor, int* __restrict__ idx, int E) {
  int e = blockIdx.x * 256 + threadIdx.x;
  if (e < E) {
    int pos = atomicAdd(&cursor[col[e]], 1);
    idx[pos] = row[e];
  }
}

// ---------------- aggregation: S[r] = sum_e norm_e * xbf[row_e], swt[r] = sum_e norm_e ----------------
// wave per output row; lane owns dims lane*4..+3. No LDS, no barriers (shfl broadcast).
__global__ __launch_bounds__(256) void agg_kernel(
    const unsigned short* __restrict__ xbf, unsigned short* __restrict__ S,
    float* __restrict__ swt, const float* __restrict__ dis,
    const int* __restrict__ indptr, const int* __restrict__ idx,
    const int* __restrict__ noi, int use_noi, int R) {
  int wave = threadIdx.x >> 6, lane = threadIdx.x & 63;
  int r = blockIdx.x * 4 + wave;
  int rc = min(r, R - 1);
  int i = use_noi ? noi[rc] : rc;
  float di = dis[i];
  float di2 = di * di;

  uint2 u = *(const uint2*)(xbf + (size_t)i * DMODEL + lane * 4);
  float a0 = di2 * bflo(u.x), a1 = di2 * bfhi(u.x);
  float a2 = di2 * bflo(u.y), a3 = di2 * bfhi(u.y);

  int s = indptr[i], e = indptr[i + 1];
  float sw = 0.f;
  for (int base = s; base < e; base += 64) {
    int n = min(64, e - base);
    int sr = 0;
    float w = 0.f;
    if (lane < n) {
      sr = idx[base + lane];
      w = dis[sr] * di;
    }
    int j = 0;
    for (; j + 4 <= n; j += 4) {
      int s0 = __shfl(sr, j), s1 = __shfl(sr, j + 1), s2 = __shfl(sr, j + 2), s3 = __shfl(sr, j + 3);
      float w0 = __shfl(w, j), w1 = __shfl(w, j + 1), w2 = __shfl(w, j + 2), w3 = __shfl(w, j + 3);
      uint2 u0 = *(const uint2*)(xbf + (size_t)s0 * DMODEL + lane * 4);
      uint2 u1 = *(const uint2*)(xbf + (size_t)s1 * DMODEL + lane * 4);
      uint2 u2 = *(const uint2*)(xbf + (size_t)s2 * DMODEL + lane * 4);
      uint2 u3 = *(const uint2*)(xbf + (size_t)s3 * DMODEL + lane * 4);
      a0 += w0 * bflo(u0.x); a1 += w0 * bfhi(u0.x); a2 += w0 * bflo(u0.y); a3 += w0 * bfhi(u0.y);
      a0 += w1 * bflo(u1.x); a1 += w1 * bfhi(u1.x); a2 += w1 * bflo(u1.y); a3 += w1 * bfhi(u1.y);
      a0 += w2 * bflo(u2.x); a1 += w2 * bfhi(u2.x); a2 += w2 * bflo(u2.y); a3 += w2 * bfhi(u2.y);
      a0 += w3 * bflo(u3.x); a1 += w3 * bfhi(u3.x); a2 += w3 * bflo(u3.y); a3 += w3 * bfhi(u3.y);
      sw += w0 + w1 + w2 + w3;
    }
    for (; j < n; ++j) {
      int sj = __shfl(sr, j);
      float wj = __shfl(w, j);
      uint2 uu = *(const uint2*)(xbf + (size_t)sj * DMODEL + lane * 4);
      a0 += wj * bflo(uu.x); a1 += wj * bfhi(uu.x); a2 += wj * bflo(uu.y); a3 += wj * bfhi(uu.y);
      sw += wj;
    }
  }
  if (r < R) {
    uint2 o = {pk2bf(a0, a1), pk2bf(a2, a3)};
    *(uint2*)(S + (size_t)r * DMODEL + lane * 4) = o;
    if (lane == 0) swt[r] = di2 + sw;
  }
}

// ---------------- fused transform: z = [Wc Sc + bc*s, Wp Sp + bp*s]; out = xin + [relu]LN(z) ----------------
// 512 threads = 8 waves; 32 rows/block. wave: mt = w&1 (row-tile), cq = w>>2? no: cq = w>>1 (col-quad 64).
// A/B frag layout verified on HW (R7): row|col = lane&15, k = (lane>>4)*8 + j; D: col=lane&15,row=(lane>>4)*4+j.
__global__ __launch_bounds__(512) void xform_kernel(
    const unsigned short* __restrict__ S, const float* __restrict__ swt,
    const unsigned short* __restrict__ Wcb, const unsigned short* __restrict__ Wpb,
    const float* __restrict__ bc, const float* __restrict__ bp,
    const float* __restrict__ gamma, const float* __restrict__ beta,
    const float* __restrict__ xin, const int* __restrict__ noi,
    float* __restrict__ xout, unsigned short* __restrict__ xbf_out,
    int use_noi, int relu, int R) {
  int t = threadIdx.x;
  int w = t >> 6, lane = t & 63;
  int mt = w & 1, cq = w >> 1;       // cq 0..3 over 256 cols
  int h = cq >> 1, cgg = cq & 1;     // half (c/p), 64-col group within half
  int lrow = lane & 15, kgrp = lane >> 4;
  int r0 = blockIdx.x * 32;

  int arow = r0 + mt * 16 + lrow;
  int arow_c = min(arow, R - 1);
  const unsigned short* ap = S + (size_t)arow_c * DMODEL + h * DCH + kgrp * 8;
  const unsigned short* Wh = h ? Wpb : Wcb;
  const float* bh = h ? bp : bc;

  int orow0 = mt * 16 + kgrp * 4;  // local row of acc element j
  float sj[4];
#pragma unroll
  for (int j = 0; j < 4; ++j) sj[j] = swt[min(r0 + orow0 + j, R - 1)];

  int colw[4];
  const unsigned short* bpw[4];
  f32x4 acc[4];
#pragma unroll
  for (int nt = 0; nt < 4; ++nt) {
    colw[nt] = cgg * 64 + nt * 16 + lrow;
    bpw[nt] = Wh + (size_t)colw[nt] * DCH + kgrp * 8;
    float bias = bh[colw[nt]];
    acc[nt] = (f32x4){bias * sj[0], bias * sj[1], bias * sj[2], bias * sj[3]};
  }

  union U8 { s16x8 v; uint4 q; };
#pragma unroll
  for (int kt = 0; kt < 4; ++kt) {
    U8 af;
    af.q = *(const uint4*)(ap + kt * 32);
#pragma unroll
    for (int nt = 0; nt < 4; ++nt) {
      U8 bf;
      bf.q = *(const uint4*)(bpw[nt] + kt * 32);
      acc[nt] = __builtin_amdgcn_mfma_f32_16x16x32_bf16(af.v, bf.v, acc[nt], 0, 0, 0);
    }
  }

  // LN partial sums: per lane, over its 4 cols, for each of its 4 rows
  float p1[4], p2[4];
#pragma unroll
  for (int j = 0; j < 4; ++j) {
    p1[j] = acc[0][j] + acc[1][j] + acc[2][j] + acc[3][j];
    p2[j] = acc[0][j] * acc[0][j] + acc[1][j] * acc[1][j] +
            acc[2][j] * acc[2][j] + acc[3][j] * acc[3][j];
  }
#pragma unroll
  for (int off = 8; off > 0; off >>= 1) {
#pragma unroll
    for (int j = 0; j < 4; ++j) {
      p1[j] += __shfl_down(p1[j], off, 16);
      p2[j] += __shfl_down(p2[j], off, 16);
    }
  }
  __shared__ float red1[32][4], red2[32][4];
  __shared__ float muS[32], rsS[32];
  if (lrow == 0) {
#pragma unroll
    for (int j = 0; j < 4; ++j) {
      red1[orow0 + j][cq] = p1[j];
      red2[orow0 + j][cq] = p2[j];
    }
  }
  __syncthreads();
  if (t < 32) {
    float s1 = red1[t][0] + red1[t][1] + red1[t][2] + red1[t][3];
    float s2 = red2[t][0] + red2[t][1] + red2[t][2] + red2[t][3];
    float mu = s1 * (1.0f / DMODEL);
    float var = s2 * (1.0f / DMODEL) - mu * mu;
    muS[t] = mu;
    rsS[t] = rsqrtf(var + LN_EPS);
  }
  __syncthreads();

#pragma unroll
  for (int nt = 0; nt < 4; ++nt) {
    int col = h * DCH + colw[nt];
    float g = gamma[col], bt = beta[col];
#pragma unroll
    for (int j = 0; j < 4; ++j) {
      int rr = orow0 + j;
      int grow = r0 + rr;
      if (grow < R) {
        float y = (acc[nt][j] - muS[rr]) * rsS[rr] * g + bt;
        if (relu) y = fmaxf(y, 0.f);
        int node = use_noi ? noi[grow] : grow;
        float o = xin[(size_t)node * DMODEL + col] + y;
        xout[(size_t)grow * DMODEL + col] = o;
        if (xbf_out) xbf_out[(size_t)grow * DMODEL + col] = f2bf(o);
      }
    }
  }
}

extern "C" void kernel_launch(void* const* d_in, const int* in_sizes, int n_in,
                              void* d_out, int out_size, void* d_ws, size_t ws_size,
                              hipStream_t stream) {
  const float* x     = (const float*)d_in[0];
  const int*   edges = (const int*)d_in[1];
  const int*   noi   = (const int*)d_in[2];
  const float* Wc    = (const float*)d_in[3];
  const float* bc    = (const float*)d_in[4];
  const float* Wp    = (const float*)d_in[5];
  const float* bp    = (const float*)d_in[6];
  const float* gamma = (const float*)d_in[7];
  const float* beta  = (const float*)d_in[8];

  int N = in_sizes[0] / DMODEL;
  int E = in_sizes[1] / 2;
  int K = in_sizes[2];
  int nwElem = in_sizes[3];  // L*DC*DC
  const int* row = edges;
  const int* col = edges + E;

  char* base = (char*)d_ws;
  size_t off = 0;
  auto alloc = [&](size_t bytes) -> void* {
    void* p = base + off;
    off += (bytes + 255) & ~(size_t)255;
    return p;
  };

  unsigned short* xbf0   = (unsigned short*)alloc((size_t)N * DMODEL * 2);
  unsigned short* xbfA   = (unsigned short*)alloc((size_t)N * DMODEL * 2);
  unsigned short* xbfB   = (unsigned short*)alloc((size_t)N * DMODEL * 2);
  unsigned short* Sb     = (unsigned short*)alloc((size_t)N * DMODEL * 2);
  float*          xA     = (float*)alloc((size_t)N * DMODEL * 4);
  float*          xB     = (float*)alloc((size_t)N * DMODEL * 4);
  unsigned short* Wcb    = (unsigned short*)alloc((size_t)nwElem * 2);
  unsigned short* Wpb    = (unsigned short*)alloc((size_t)nwElem * 2);
  float*          swt    = (float*)alloc((size_t)N * 4);
  float*          dis    = (float*)alloc((size_t)N * 4);
  int*            cnt    = (int*)alloc((size_t)2 * N * 4);
  int*            indptr = (int*)alloc((size_t)(N + 1) * 4);
  int*            cursor = (int*)alloc((size_t)N * 4);
  int*            idx    = (int*)alloc((size_t)E * 4);

  hipMemsetAsync(cnt, 0, (size_t)2 * N * 4, stream);

  int nx8 = (N * DMODEL) / 8;
  int nw8 = nwElem / 8;
  int mx = E > nx8 ? E : nx8;
  if (nw8 > mx) mx = nw8;
  hist_cvt_kernel<<<(mx + 255) / 256, 256, 0, stream>>>(
      row, col, cnt, cnt + N, E, x, xbf0, nx8, Wc, Wcb, Wp, Wpb, nw8);
  scan_dis_kernel<<<1, 256, 0, stream>>>(cnt + N, cnt, indptr, cursor, dis, N, E);
  fill_kernel<<<(E + 255) / 256, 256, 0, stream>>>(row, col, cursor, idx, E);

  // layer 0
  agg_kernel<<<(N + 3) / 4, 256, 0, stream>>>(xbf0, Sb, swt, dis, indptr, idx, nullptr, 0, N);
  xform_kernel<<<(N + 31) / 32, 512, 0, stream>>>(
      Sb, swt, Wcb, Wpb, bc, bp, gamma, beta, x, nullptr, xA, xbfA, 0, 1, N);
  // layer 1
  agg_kernel<<<(N + 3) / 4, 256, 0, stream>>>(xbfA, Sb, swt, dis, indptr, idx, nullptr, 0, N);
  xform_kernel<<<(N + 31) / 32, 512, 0, stream>>>(
      Sb, swt, Wcb + (size_t)DCH * DCH, Wpb + (size_t)DCH * DCH, bc + DCH, bp + DCH,
      gamma + DMODEL, beta + DMODEL, xA, nullptr, xB, xbfB, 0, 1, N);
  // layer 2 (only noi rows)
  agg_kernel<<<(K + 3) / 4, 256, 0, stream>>>(xbfB, Sb, swt, dis, indptr, idx, noi, 1, K);
  xform_kernel<<<(K + 31) / 32, 512, 0, stream>>>(
      Sb, swt, Wcb + (size_t)2 * DCH * DCH, Wpb + (size_t)2 * DCH * DCH, bc + 2 * DCH, bp + 2 * DCH,
      gamma + 2 * DMODEL, beta + 2 * DMODEL, xB, noi, (float*)d_out, nullptr, 1, 0, K);
}